// Round 1
// 1293.203 us; speedup vs baseline: 1.1979x; 1.1979x over previous
//
#include <hip/hip_runtime.h>

typedef __bf16 bf16;
typedef __attribute__((ext_vector_type(8))) __bf16 bf16x8;
typedef __attribute__((ext_vector_type(4))) float f32x4;

#define MFMA_BF16(a,b,c) __builtin_amdgcn_mfma_f32_16x16x32_bf16((a),(b),(c),0,0,0)

__device__ __forceinline__ void gld_lds16(const void* g, void* l) {
  __builtin_amdgcn_global_load_lds(
      (__attribute__((address_space(1))) void*)(g),
      (__attribute__((address_space(3))) void*)(l), 16, 0, 0);
}

__device__ __forceinline__ bf16x8 cvt8(float4 u, float4 v) {
  bf16x8 r;
  r[0] = (bf16)u.x; r[1] = (bf16)u.y; r[2] = (bf16)u.z; r[3] = (bf16)u.w;
  r[4] = (bf16)v.x; r[5] = (bf16)v.y; r[6] = (bf16)v.z; r[7] = (bf16)v.w;
  return r;
}

__global__ __launch_bounds__(256) void fill_kernel(float* p, int n, float v) {
  int i = blockIdx.x * 256 + threadIdx.x;
  if (i < n) p[i] = v;
}

// fp32 -> bf16, 4 elems/thread (16B coalesced loads, 8B stores)
__global__ __launch_bounds__(256) void cvt_kernel(const float* __restrict__ s, bf16* __restrict__ d) {
  size_t i = ((size_t)blockIdx.x * 256 + threadIdx.x) * 4;
  float4 a = *(const float4*)(s + i);
  ushort4 r;
  r.x = __builtin_bit_cast(unsigned short, (bf16)a.x);
  r.y = __builtin_bit_cast(unsigned short, (bf16)a.y);
  r.z = __builtin_bit_cast(unsigned short, (bf16)a.z);
  r.w = __builtin_bit_cast(unsigned short, (bf16)a.w);
  *(ushort4*)(d + i) = r;
}

// ---------------- pure-bf16 m97-style GEMM (A bf16, W bf16) ----------------
// C[m][n] = sum_k A[m][k]*W[n][k]. z==2 -> VT transposed epilogue (b,h,d,s).
__global__ __launch_bounds__(256) void gemm_bt_bf(
    const bf16* __restrict__ A,
    const bf16* __restrict__ W0, const bf16* __restrict__ W1, const bf16* __restrict__ W2,
    bf16* __restrict__ C0, bf16* __restrict__ C1, bf16* __restrict__ C2)
{
  constexpr int K = 4096, N = 4096;
  __shared__ __align__(16) bf16 As[128 * 32];
  __shared__ __align__(16) bf16 Bs[128 * 32];
  const int z = blockIdx.z;
  const bf16* __restrict__ W = (z == 0) ? W0 : ((z == 1) ? W1 : W2);
  bf16* __restrict__ C = (z == 0) ? C0 : ((z == 1) ? C1 : C2);
  const int tid = threadIdx.x;
  const int lane = tid & 63, wave = tid >> 6;
  const int l15 = lane & 15, quad = lane >> 4;
  const int m0 = blockIdx.x * 128, n0 = blockIdx.y * 128;
  const int wm = (wave & 1) * 64, wn = (wave >> 1) * 64;

  const int srow = tid >> 2;          // 0..63
  const int scol = (tid & 3) * 8;     // elems
  const bf16* gA = A + (size_t)(m0 + srow) * K + scol;
  const bf16* gW = W + (size_t)(n0 + srow) * K + scol;
  bf16* lA = &As[srow * 32 + scol];
  bf16* lB = &Bs[srow * 32 + scol];

  f32x4 acc[4][4];
#pragma unroll
  for (int i = 0; i < 4; i++)
#pragma unroll
    for (int j = 0; j < 4; j++) acc[i][j] = (f32x4){0.f, 0.f, 0.f, 0.f};

  for (int k0 = 0; k0 < K; k0 += 32) {
    __syncthreads();
    gld_lds16(gA + k0,                  lA);
    gld_lds16(gA + k0 + (size_t)64 * K, lA + 64 * 32);
    gld_lds16(gW + k0,                  lB);
    gld_lds16(gW + k0 + (size_t)64 * K, lB + 64 * 32);
    __syncthreads();
    bf16x8 af[4], bfr[4];
#pragma unroll
    for (int i = 0; i < 4; i++) af[i]  = *(const bf16x8*)&As[(wm + i * 16 + l15) * 32 + quad * 8];
#pragma unroll
    for (int j = 0; j < 4; j++) bfr[j] = *(const bf16x8*)&Bs[(wn + j * 16 + l15) * 32 + quad * 8];
#pragma unroll
    for (int i = 0; i < 4; i++)
#pragma unroll
      for (int j = 0; j < 4; j++)
        acc[i][j] = MFMA_BF16(af[i], bfr[j], acc[i][j]);
  }

  if (z == 2) {
#pragma unroll
    for (int i = 0; i < 4; i++) {
      const int mg = m0 + wm + i * 16 + quad * 4;
      const int bb = mg >> 11, ss = mg & 2047;
#pragma unroll
      for (int j = 0; j < 4; j++) {
        const int n = n0 + wn + j * 16 + l15;
        ushort4 pk;
        pk.x = __builtin_bit_cast(unsigned short, (bf16)acc[i][j][0]);
        pk.y = __builtin_bit_cast(unsigned short, (bf16)acc[i][j][1]);
        pk.z = __builtin_bit_cast(unsigned short, (bf16)acc[i][j][2]);
        pk.w = __builtin_bit_cast(unsigned short, (bf16)acc[i][j][3]);
        *(ushort4*)&C[((size_t)bb * 4096 + n) * 2048 + ss] = pk;
      }
    }
  } else {
#pragma unroll
    for (int i = 0; i < 4; i++) {
      const int row = m0 + wm + i * 16 + quad * 4;
#pragma unroll
      for (int j = 0; j < 4; j++) {
        const int col = n0 + wn + j * 16 + l15;
#pragma unroll
        for (int r = 0; r < 4; r++)
          C[(size_t)(row + r) * N + col] = (bf16)acc[i][j][r];
      }
    }
  }
}

// same body, single output, fp32 epilogue
__global__ __launch_bounds__(256) void gemm_out_bf(
    const bf16* __restrict__ A, const bf16* __restrict__ W, float* __restrict__ C)
{
  constexpr int K = 4096, N = 4096;
  __shared__ __align__(16) bf16 As[128 * 32];
  __shared__ __align__(16) bf16 Bs[128 * 32];
  const int tid = threadIdx.x;
  const int lane = tid & 63, wave = tid >> 6;
  const int l15 = lane & 15, quad = lane >> 4;
  const int m0 = blockIdx.x * 128, n0 = blockIdx.y * 128;
  const int wm = (wave & 1) * 64, wn = (wave >> 1) * 64;

  const int srow = tid >> 2;
  const int scol = (tid & 3) * 8;
  const bf16* gA = A + (size_t)(m0 + srow) * K + scol;
  const bf16* gW = W + (size_t)(n0 + srow) * K + scol;
  bf16* lA = &As[srow * 32 + scol];
  bf16* lB = &Bs[srow * 32 + scol];

  f32x4 acc[4][4];
#pragma unroll
  for (int i = 0; i < 4; i++)
#pragma unroll
    for (int j = 0; j < 4; j++) acc[i][j] = (f32x4){0.f, 0.f, 0.f, 0.f};

  for (int k0 = 0; k0 < K; k0 += 32) {
    __syncthreads();
    gld_lds16(gA + k0,                  lA);
    gld_lds16(gA + k0 + (size_t)64 * K, lA + 64 * 32);
    gld_lds16(gW + k0,                  lB);
    gld_lds16(gW + k0 + (size_t)64 * K, lB + 64 * 32);
    __syncthreads();
    bf16x8 af[4], bfr[4];
#pragma unroll
    for (int i = 0; i < 4; i++) af[i]  = *(const bf16x8*)&As[(wm + i * 16 + l15) * 32 + quad * 8];
#pragma unroll
    for (int j = 0; j < 4; j++) bfr[j] = *(const bf16x8*)&Bs[(wn + j * 16 + l15) * 32 + quad * 8];
#pragma unroll
    for (int i = 0; i < 4; i++)
#pragma unroll
      for (int j = 0; j < 4; j++)
        acc[i][j] = MFMA_BF16(af[i], bfr[j], acc[i][j]);
  }

#pragma unroll
  for (int i = 0; i < 4; i++) {
    const int row = m0 + wm + i * 16 + quad * 4;
#pragma unroll
    for (int j = 0; j < 4; j++) {
      const int col = n0 + wn + j * 16 + l15;
#pragma unroll
      for (int r = 0; r < 4; r++)
        C[(size_t)(row + r) * N + col] = acc[i][j][r];
    }
  }
}

// ---------------- fallback QKV GEMM (fp32 inputs, manual staging) ----------------
__global__ __launch_bounds__(256) void gemm_f32in(
    const float* __restrict__ A,
    const float* __restrict__ W0, const float* __restrict__ W1, const float* __restrict__ W2,
    bf16* __restrict__ C0, bf16* __restrict__ C1, bf16* __restrict__ C2)
{
  constexpr int K = 4096, N = 4096;
  __shared__ __align__(16) bf16 As[128 * 32];
  __shared__ __align__(16) bf16 Bs[128 * 32];
  const int z = blockIdx.z;
  const float* __restrict__ W = (z == 0) ? W0 : ((z == 1) ? W1 : W2);
  bf16* __restrict__ C = (z == 0) ? C0 : ((z == 1) ? C1 : C2);
  const int tid = threadIdx.x;
  const int lane = tid & 63, wave = tid >> 6;
  const int l15 = lane & 15, quad = lane >> 4;
  const int m0 = blockIdx.x * 128, n0 = blockIdx.y * 128;
  const int wm = (wave & 1) * 64, wn = (wave >> 1) * 64;

  const int srow = tid >> 2;
  const int scol = (tid & 3) * 8;
  const float* gA = A + (size_t)(m0 + srow) * K + scol;
  const float* gW = W + (size_t)(n0 + srow) * K + scol;
  bf16* lA = &As[srow * 32 + scol];
  bf16* lB = &Bs[srow * 32 + scol];

  f32x4 acc[4][4];
#pragma unroll
  for (int i = 0; i < 4; i++)
#pragma unroll
    for (int j = 0; j < 4; j++) acc[i][j] = (f32x4){0.f, 0.f, 0.f, 0.f};

  for (int k0 = 0; k0 < K; k0 += 32) {
    float4 a0 = *(const float4*)(gA + k0);
    float4 a1 = *(const float4*)(gA + k0 + 4);
    float4 a2 = *(const float4*)(gA + k0 + (size_t)64 * K);
    float4 a3 = *(const float4*)(gA + k0 + (size_t)64 * K + 4);
    float4 b0 = *(const float4*)(gW + k0);
    float4 b1 = *(const float4*)(gW + k0 + 4);
    float4 b2 = *(const float4*)(gW + k0 + (size_t)64 * K);
    float4 b3 = *(const float4*)(gW + k0 + (size_t)64 * K + 4);
    __syncthreads();
    *(bf16x8*)lA              = cvt8(a0, a1);
    *(bf16x8*)(lA + 64 * 32)  = cvt8(a2, a3);
    *(bf16x8*)lB              = cvt8(b0, b1);
    *(bf16x8*)(lB + 64 * 32)  = cvt8(b2, b3);
    __syncthreads();
    bf16x8 af[4], bfr[4];
#pragma unroll
    for (int i = 0; i < 4; i++) af[i]  = *(const bf16x8*)&As[(wm + i * 16 + l15) * 32 + quad * 8];
#pragma unroll
    for (int j = 0; j < 4; j++) bfr[j] = *(const bf16x8*)&Bs[(wn + j * 16 + l15) * 32 + quad * 8];
#pragma unroll
    for (int i = 0; i < 4; i++)
#pragma unroll
      for (int j = 0; j < 4; j++)
        acc[i][j] = MFMA_BF16(af[i], bfr[j], acc[i][j]);
  }

  if (z == 2) {
#pragma unroll
    for (int i = 0; i < 4; i++) {
      const int mg = m0 + wm + i * 16 + quad * 4;
      const int bb = mg >> 11, ss = mg & 2047;
#pragma unroll
      for (int j = 0; j < 4; j++) {
        const int n = n0 + wn + j * 16 + l15;
        ushort4 pk;
        pk.x = __builtin_bit_cast(unsigned short, (bf16)acc[i][j][0]);
        pk.y = __builtin_bit_cast(unsigned short, (bf16)acc[i][j][1]);
        pk.z = __builtin_bit_cast(unsigned short, (bf16)acc[i][j][2]);
        pk.w = __builtin_bit_cast(unsigned short, (bf16)acc[i][j][3]);
        *(ushort4*)&C[((size_t)bb * 4096 + n) * 2048 + ss] = pk;
      }
    }
  } else {
#pragma unroll
    for (int i = 0; i < 4; i++) {
      const int row = m0 + wm + i * 16 + quad * 4;
#pragma unroll
      for (int j = 0; j < 4; j++) {
        const int col = n0 + wn + j * 16 + l15;
#pragma unroll
        for (int r = 0; r < 4; r++)
          C[(size_t)(row + r) * N + col] = (bf16)acc[i][j][r];
      }
    }
  }
}

// Interleaved RoPE on q and k (bf16) in-place; freqs fp32.
__global__ __launch_bounds__(256) void rope_kernel(
    bf16* __restrict__ q, bf16* __restrict__ kk,
    const float* __restrict__ fc, const float* __restrict__ fs)
{
  const int t = blockIdx.x * 256 + threadIdx.x;
  const int i4 = (t & 15) << 2;
  const int row = t >> 4;
  const int s = (row >> 5) & 2047;

  float4 c4 = *(const float4*)(fc + s * 64 + i4);
  float4 s4 = *(const float4*)(fs + s * 64 + i4);
  float c[4]  = {c4.x, c4.y, c4.z, c4.w};
  float sn[4] = {s4.x, s4.y, s4.z, s4.w};

  const int off = row * 128 + (i4 << 1);
  uint4 qv = *(const uint4*)(q + off);
  uint4 kv = *(const uint4*)(kk + off);
  unsigned qa[4] = {qv.x, qv.y, qv.z, qv.w};
  unsigned ka[4] = {kv.x, kv.y, kv.z, kv.w};
#pragma unroll
  for (int p = 0; p < 4; p++) {
    float x0 = __builtin_bit_cast(float, (qa[p] & 0xffffu) << 16);
    float x1 = __builtin_bit_cast(float, (qa[p] >> 16) << 16);
    unsigned lo = __builtin_bit_cast(unsigned short, (bf16)(x0 * c[p] - x1 * sn[p]));
    unsigned hi = __builtin_bit_cast(unsigned short, (bf16)(x0 * sn[p] + x1 * c[p]));
    qa[p] = lo | (hi << 16);
    float y0 = __builtin_bit_cast(float, (ka[p] & 0xffffu) << 16);
    float y1 = __builtin_bit_cast(float, (ka[p] >> 16) << 16);
    lo = __builtin_bit_cast(unsigned short, (bf16)(y0 * c[p] - y1 * sn[p]));
    hi = __builtin_bit_cast(unsigned short, (bf16)(y0 * sn[p] + y1 * c[p]));
    ka[p] = lo | (hi << 16);
  }
  *(uint4*)(q + off)  = make_uint4(qa[0], qa[1], qa[2], qa[3]);
  *(uint4*)(kk + off) = make_uint4(ka[0], ka[1], ka[2], ka[3]);
}

// Flash attention v2: causal, 64 q-rows/block, 128-key chunks.
// LDS: Q 16K | K 32K | V 32K = 80 KB; P (4 waves x 16 x 136) overlaps dead Q + K head.
// Q/K/V tiles use the st-16B XOR swizzle (chunk ^= row&7) to kill the D=128
// row-major ds_read_b128 bank conflicts (Guideline 4).  global_load_lds writes
// linearly, so the involution is applied on the per-lane GLOBAL source address
// and again on the LDS read offset (both-sides-or-neither, rule 21).
__global__ __launch_bounds__(256) void flash_attn(
    const bf16* __restrict__ Kg_, const bf16* __restrict__ VT, bf16* __restrict__ QO)
{
  __shared__ __align__(16) char smem[81920];
  bf16* Qs = (bf16*)smem;
  bf16* Ks = (bf16*)(smem + 16384);
  bf16* Vs = (bf16*)(smem + 49152);

  const int tid = threadIdx.x, lane = tid & 63, wave = tid >> 6;
  const int l15 = lane & 15, quad = lane >> 4;
  const int r7 = l15 & 7;                       // row&7 for all fragment rows
  const int q0 = blockIdx.x * 64, h = blockIdx.y, b = blockIdx.z;

  bf16* Qg       = QO  + ((size_t)(b * 2048 + q0) * 32 + h) * 128;
  const bf16* Kg = Kg_ + ((size_t)b * 2048 * 32 + h) * 128;
  const bf16* Vg = VT  + ((size_t)(b * 32 + h)) * 128 * 2048;

#pragma unroll
  for (int it = 0; it < 4; ++it) {
    int c = it * 256 + tid;
    int rr = c >> 4, cc = (c & 15) ^ (rr & 7);      // pre-swizzled source
    gld_lds16(Qg + (size_t)rr * 4096 + cc * 8, &Qs[c * 8]);
  }
  __syncthreads();
  bf16x8 qf[4];
#pragma unroll
  for (int ks = 0; ks < 4; ks++)
    qf[ks] = *(const bf16x8*)&Qs[(wave * 16 + l15) * 128 + (((ks * 4 + quad) ^ r7) * 8)];

  bf16* Ps = (bf16*)smem + wave * (16 * 136);   // 17408 B total, overlaps Q + K[0:512)

  float m_i[4], l_i[4];
  f32x4 oacc[8];
#pragma unroll
  for (int r = 0; r < 4; r++) { m_i[r] = -INFINITY; l_i[r] = 0.f; }
#pragma unroll
  for (int j = 0; j < 8; j++) oacc[j] = (f32x4){0.f, 0.f, 0.f, 0.f};

  const float SCL = 0.08838834764831845f * 1.4426950408889634f;

  const int nct = (blockIdx.x >> 1) + 1;   // ceil((q0+64)/128)
  for (int ct = 0; ct < nct; ++ct) {
    __syncthreads();   // prev PV reads done; safe to restage K/V (and clobber P residue)
    const bf16* Kt = Kg + (size_t)ct * 128 * 4096;
    const bf16* Vt = Vg + ct * 128;
#pragma unroll
    for (int it = 0; it < 8; ++it) {
      int c = it * 256 + tid;   // 0..2047
      int rr = c >> 4, cc = (c & 15) ^ (rr & 7);    // pre-swizzled source
      gld_lds16(Kt + (size_t)rr * 4096 + cc * 8, &Ks[c * 8]);
      gld_lds16(Vt + (size_t)rr * 2048 + cc * 8, &Vs[c * 8]);
    }
    __syncthreads();

    f32x4 sacc[8];
#pragma unroll
    for (int nb = 0; nb < 8; nb++) {
      f32x4 a = (f32x4){0.f, 0.f, 0.f, 0.f};
#pragma unroll
      for (int ks = 0; ks < 4; ks++) {
        bf16x8 kf = *(const bf16x8*)&Ks[(nb * 16 + l15) * 128 + (((ks * 4 + quad) ^ r7) * 8)];
        a = MFMA_BF16(qf[ks], kf, a);
      }
      sacc[nb] = a;
    }

    const int qb = q0 + wave * 16 + quad * 4;
    const int kbase = ct * 128 + l15;
    float alpha[4];
#pragma unroll
    for (int r = 0; r < 4; r++) {
      float mx = -INFINITY;
#pragma unroll
      for (int nb = 0; nb < 8; nb++) {
        float s = sacc[nb][r] * SCL;
        if (kbase + nb * 16 > qb + r) s = -INFINITY;
        sacc[nb][r] = s;
        mx = fmaxf(mx, s);
      }
#pragma unroll
      for (int off = 1; off < 16; off <<= 1) mx = fmaxf(mx, __shfl_xor(mx, off));
      float mn = fmaxf(m_i[r], mx);
      alpha[r] = exp2f(m_i[r] - mn);
      m_i[r] = mn;
      float rs = 0.f;
#pragma unroll
      for (int nb = 0; nb < 8; nb++) {
        float p = exp2f(sacc[nb][r] - mn);
        rs += p;
        Ps[(quad * 4 + r) * 136 + nb * 16 + l15] = (bf16)p;
      }
#pragma unroll
      for (int off = 1; off < 16; off <<= 1) rs += __shfl_xor(rs, off);
      l_i[r] = l_i[r] * alpha[r] + rs;
    }
#pragma unroll
    for (int j = 0; j < 8; j++)
#pragma unroll
      for (int r = 0; r < 4; r++) oacc[j][r] *= alpha[r];

    __syncthreads();   // P visible

#pragma unroll
    for (int ks2 = 0; ks2 < 4; ks2++) {
      bf16x8 pf = *(const bf16x8*)&Ps[l15 * 136 + ks2 * 32 + quad * 8];
#pragma unroll
      for (int j = 0; j < 8; j++) {
        bf16x8 vf = *(const bf16x8*)&Vs[(j * 16 + l15) * 128 + (((ks2 * 4 + quad) ^ r7) * 8)];
        oacc[j] = MFMA_BF16(pf, vf, oacc[j]);
      }
    }
  }

#pragma unroll
  for (int r = 0; r < 4; r++) {
    const float inv = 1.f / l_i[r];
    const int row = q0 + wave * 16 + quad * 4 + r;
    bf16* Og = QO + ((size_t)(b * 2048 + row) * 32 + h) * 128;
#pragma unroll
    for (int j = 0; j < 8; j++) Og[j * 16 + l15] = (bf16)(oacc[j][r] * inv);
  }
}

extern "C" void kernel_launch(void* const* d_in, const int* in_sizes, int n_in,
                              void* d_out, int out_size, void* d_ws, size_t ws_size,
                              hipStream_t stream) {
  const float* x  = (const float*)d_in[0];
  const float* wq = (const float*)d_in[1];
  const float* wk = (const float*)d_in[2];
  const float* wv = (const float*)d_in[3];
  const float* wo = (const float*)d_in[4];
  const float* fc = (const float*)d_in[5];
  const float* fs = (const float*)d_in[6];
  float* out = (float*)d_out;

  float sentinel = 0.f;
  if (n_in < 9 || in_sizes[0] != 16777216) sentinel = 200.f;
  else if (out_size != 16777216)           sentinel = 300.f;
  else if (in_sizes[5] != 131072)          sentinel = 400.f;
  else if (ws_size < 3ull * 33554432ull)   sentinel = 100.f;
  if (sentinel != 0.f) {
    fill_kernel<<<dim3((out_size + 255) / 256), dim3(256), 0, stream>>>(out, out_size, sentinel);
    return;
  }

  bf16* q  = (bf16*)d_ws;                    // becomes attention output in-place
  bf16* k  = q  + (size_t)16777216;          // later reused for bf16(wo)
  bf16* vt = k  + (size_t)16777216;

  dim3 blk(256, 1, 1);
  const bool bigws = (ws_size >= 7ull * 33554432ull);   // 224 MiB

  if (bigws) {
    bf16* xb  = vt  + (size_t)16777216;
    bf16* wqb = xb  + (size_t)16777216;
    bf16* wkb = wqb + (size_t)16777216;
    bf16* wvb = wkb + (size_t)16777216;
    cvt_kernel<<<dim3(16384), blk, 0, stream>>>(x,  xb);
    cvt_kernel<<<dim3(16384), blk, 0, stream>>>(wq, wqb);
    cvt_kernel<<<dim3(16384), blk, 0, stream>>>(wk, wkb);
    cvt_kernel<<<dim3(16384), blk, 0, stream>>>(wv, wvb);
    gemm_bt_bf<<<dim3(32, 32, 3), blk, 0, stream>>>(xb, wqb, wkb, wvb, q, k, vt);
  } else {
    gemm_f32in<<<dim3(32, 32, 3), blk, 0, stream>>>(x, wq, wk, wv, q, k, vt);
  }
  rope_kernel<<<dim3(8192), blk, 0, stream>>>(q, k, fc, fs);
  flash_attn<<<dim3(32, 32, 2), blk, 0, stream>>>(k, vt, q);
  cvt_kernel<<<dim3(16384), blk, 0, stream>>>(wo, k);          // k buffer now dead -> bf16(wo)
  gemm_out_bf<<<dim3(32, 32, 1), blk, 0, stream>>>(q, k, out);
}

// Round 2
// 1178.160 us; speedup vs baseline: 1.3148x; 1.0976x over previous
//
#include <hip/hip_runtime.h>

typedef __bf16 bf16;
typedef __attribute__((ext_vector_type(8))) __bf16 bf16x8;
typedef __attribute__((ext_vector_type(4))) float f32x4;

#define MFMA_BF16(a,b,c) __builtin_amdgcn_mfma_f32_16x16x32_bf16((a),(b),(c),0,0,0)

__device__ __forceinline__ void gld_lds16(const void* g, void* l) {
  __builtin_amdgcn_global_load_lds(
      (__attribute__((address_space(1))) void*)(g),
      (__attribute__((address_space(3))) void*)(l), 16, 0, 0);
}

__device__ __forceinline__ bf16x8 cvt8(float4 u, float4 v) {
  bf16x8 r;
  r[0] = (bf16)u.x; r[1] = (bf16)u.y; r[2] = (bf16)u.z; r[3] = (bf16)u.w;
  r[4] = (bf16)v.x; r[5] = (bf16)v.y; r[6] = (bf16)v.z; r[7] = (bf16)v.w;
  return r;
}

__global__ __launch_bounds__(256) void fill_kernel(float* p, int n, float v) {
  int i = blockIdx.x * 256 + threadIdx.x;
  if (i < n) p[i] = v;
}

// fp32 -> bf16, 4 elems/thread
__global__ __launch_bounds__(256) void cvt_kernel(const float* __restrict__ s, bf16* __restrict__ d) {
  size_t i = ((size_t)blockIdx.x * 256 + threadIdx.x) * 4;
  float4 a = *(const float4*)(s + i);
  ushort4 r;
  r.x = __builtin_bit_cast(unsigned short, (bf16)a.x);
  r.y = __builtin_bit_cast(unsigned short, (bf16)a.y);
  r.z = __builtin_bit_cast(unsigned short, (bf16)a.z);
  r.w = __builtin_bit_cast(unsigned short, (bf16)a.w);
  *(ushort4*)(d + i) = r;
}

// ================= 256x256 8-wave counted-vmcnt GEMM core =================
// C[m][n] = sum_k A[m][k]*W[n][k], K = N = 4096, BK = 64.
// LDS per buf: [A ks0 16K][A ks1 16K][B ks0 16K][B ks1 16K] = 64K; 2 bufs = 128K.
// Within a 16K (op,ks) block: 1024 chunks of 16B, slot s viewed as
// [row' = s>>3][c8 = s&7], holding global chunk (r = row'*2 + (y>>2), c2 = y&3)
// with y = c8 ^ (row'&7)  -- XOR swizzle, conflict-free ds_read_b128.
// Staging pre-swizzles the per-lane GLOBAL source; LDS dest stays linear.
// Gates: vmcnt(4) before ks0 phases and before ks1 phases (never 0 in loop).

template<int IH, int KS>
__device__ __forceinline__ void mfma_phase(const char* rb, int sA, int sB,
                                           f32x4 (&acc)[8][4], bf16x8 (&bq)[4])
{
  bf16x8 afr[4];
#pragma unroll
  for (int i2 = 0; i2 < 4; ++i2)
    afr[i2] = *(const bf16x8*)(rb + KS * 16384 + sA + (IH * 4 + i2) * 1024);
  if (IH == 0) {
#pragma unroll
    for (int j = 0; j < 4; ++j)
      bq[j] = *(const bf16x8*)(rb + 32768 + KS * 16384 + sB + j * 1024);
  }
  __builtin_amdgcn_s_barrier();
  __builtin_amdgcn_s_setprio(1);
#pragma unroll
  for (int i2 = 0; i2 < 4; ++i2)
#pragma unroll
    for (int j = 0; j < 4; ++j)
      acc[IH * 4 + i2][j] = MFMA_BF16(afr[i2], bq[j], acc[IH * 4 + i2][j]);
  __builtin_amdgcn_s_setprio(0);
}

__device__ __forceinline__ void gemm256_core(
    const bf16* __restrict__ Ag, const bf16* __restrict__ Wg,
    char* smem, int m0, int n0, f32x4 (&acc)[8][4])
{
  constexpr int NT = 64;   // 4096 / 64
  const int tid = threadIdx.x;                 // 0..511
  const int lane = tid & 63;
  const int l15 = lane & 15, quad = lane >> 4;
  const int wave = tid >> 6;
  const int wm = wave >> 2, wn = wave & 3;

  // per-lane ds_read base byte offsets within a 16K (op,ks) block
  const int swz = (((l15 & 1) * 4 + quad) ^ (l15 >> 1));
  const int sA = ((wm * 64 + (l15 >> 1)) * 8 + swz) * 16;
  const int sB = ((wn * 32 + (l15 >> 1)) * 8 + swz) * 16;

  // stage source decomposition (pre-swizzled global addr for linear LDS slot)
  int r0, c0, r1, c1;
  { int s = tid;       int rp = s >> 3, y = (s & 7) ^ (rp & 7); r0 = rp * 2 + (y >> 2); c0 = y & 3; }
  { int s = 512 + tid; int rp = s >> 3, y = (s & 7) ^ (rp & 7); r1 = rp * 2 + (y >> 2); c1 = y & 3; }

  const bf16* gA0 = Ag + (size_t)(m0 + r0) * 4096 + c0 * 8;
  const bf16* gA1 = Ag + (size_t)(m0 + r1) * 4096 + c1 * 8;
  const bf16* gB0 = Wg + (size_t)(n0 + r0) * 4096 + c0 * 8;
  const bf16* gB1 = Wg + (size_t)(n0 + r1) * 4096 + c1 * 8;

  const int d0 = tid * 16, d1 = (512 + tid) * 16;

#pragma unroll
  for (int i = 0; i < 8; i++)
#pragma unroll
    for (int j = 0; j < 4; j++) acc[i][j] = (f32x4){0.f, 0.f, 0.f, 0.f};

  // prologue: tile 0 into buf0, order A-c0, B-c0, A-c1, B-c1
  gld_lds16(gA0,      smem + d0);          gld_lds16(gA1,      smem + d1);
  gld_lds16(gB0,      smem + 32768 + d0);  gld_lds16(gB1,      smem + 32768 + d1);
  gld_lds16(gA0 + 32, smem + 16384 + d0);  gld_lds16(gA1 + 32, smem + 16384 + d1);
  gld_lds16(gB0 + 32, smem + 49152 + d0);  gld_lds16(gB1 + 32, smem + 49152 + d1);

#pragma unroll 2
  for (int t = 0; t < NT; ++t) {
    const int p = t & 1;
    const char* rb = smem + p * 65536;
    char* wb = smem + (p ^ 1) * 65536;
    const int kn = (t + 1) * 64;
    const bool st = (t + 1 < NT);

    // G0: tile-t col0 landed (4 newest in flight allowed)
    asm volatile("s_waitcnt vmcnt(4)" ::: "memory");
    __builtin_amdgcn_s_barrier();

    bf16x8 bq0[4];
    // P0: stage A-col0(t+1); compute (ih0, ks0)
    if (st) { gld_lds16(gA0 + kn, wb + d0); gld_lds16(gA1 + kn, wb + d1); }
    mfma_phase<0, 0>(rb, sA, sB, acc, bq0);
    __builtin_amdgcn_s_barrier();

    // P1: stage B-col0(t+1); compute (ih1, ks0)
    if (st) { gld_lds16(gB0 + kn, wb + 32768 + d0); gld_lds16(gB1 + kn, wb + 32768 + d1); }
    mfma_phase<1, 0>(rb, sA, sB, acc, bq0);

    // G1: tile-t col1 landed
    if (st) asm volatile("s_waitcnt vmcnt(4)" ::: "memory");
    else    asm volatile("s_waitcnt vmcnt(0)" ::: "memory");
    __builtin_amdgcn_s_barrier();

    bf16x8 bq1[4];
    // P2: stage A-col1(t+1); compute (ih0, ks1)
    if (st) { gld_lds16(gA0 + kn + 32, wb + 16384 + d0); gld_lds16(gA1 + kn + 32, wb + 16384 + d1); }
    mfma_phase<0, 1>(rb, sA, sB, acc, bq1);
    __builtin_amdgcn_s_barrier();

    // P3: stage B-col1(t+1); compute (ih1, ks1)
    if (st) { gld_lds16(gB0 + kn + 32, wb + 49152 + d0); gld_lds16(gB1 + kn + 32, wb + 49152 + d1); }
    mfma_phase<1, 1>(rb, sA, sB, acc, bq1);
  }
}

// QKV triple GEMM, bf16 out; z==2 -> VT transposed epilogue (b,h,d,s)
__global__ __launch_bounds__(512) void gemm256_qkv(
    const bf16* __restrict__ A,
    const bf16* __restrict__ W0, const bf16* __restrict__ W1, const bf16* __restrict__ W2,
    bf16* __restrict__ C0, bf16* __restrict__ C1, bf16* __restrict__ C2)
{
  __shared__ __align__(16) char smem[131072];
  const int z = blockIdx.z;
  const bf16* __restrict__ W = (z == 0) ? W0 : ((z == 1) ? W1 : W2);
  bf16* __restrict__ C = (z == 0) ? C0 : ((z == 1) ? C1 : C2);

  const int bid = blockIdx.x;                  // 0..255
  const int swb = (bid & 7) * 32 + (bid >> 3); // bijective XCD swizzle
  const int m0 = (swb & 15) << 8;
  const int n0 = (swb >> 4) << 8;

  f32x4 acc[8][4];
  gemm256_core(A, W, smem, m0, n0, acc);

  const int tid = threadIdx.x, lane = tid & 63, wave = tid >> 6;
  const int l15 = lane & 15, quad = lane >> 4;
  const int wm = wave >> 2, wn = wave & 3;

  if (z == 2) {
#pragma unroll
    for (int i = 0; i < 8; i++) {
      const int mg = m0 + wm * 128 + i * 16 + quad * 4;
      const int bb = mg >> 11, ss = mg & 2047;
#pragma unroll
      for (int j = 0; j < 4; j++) {
        const int n = n0 + wn * 64 + j * 16 + l15;
        ushort4 pk;
        pk.x = __builtin_bit_cast(unsigned short, (bf16)acc[i][j][0]);
        pk.y = __builtin_bit_cast(unsigned short, (bf16)acc[i][j][1]);
        pk.z = __builtin_bit_cast(unsigned short, (bf16)acc[i][j][2]);
        pk.w = __builtin_bit_cast(unsigned short, (bf16)acc[i][j][3]);
        *(ushort4*)&C[((size_t)bb * 4096 + n) * 2048 + ss] = pk;
      }
    }
  } else {
#pragma unroll
    for (int i = 0; i < 8; i++) {
      const int row = m0 + wm * 128 + i * 16 + quad * 4;
#pragma unroll
      for (int j = 0; j < 4; j++) {
        const int col = n0 + wn * 64 + j * 16 + l15;
#pragma unroll
        for (int r = 0; r < 4; r++)
          C[(size_t)(row + r) * 4096 + col] = (bf16)acc[i][j][r];
      }
    }
  }
}

// single GEMM, fp32 out
__global__ __launch_bounds__(512) void gemm256_out(
    const bf16* __restrict__ A, const bf16* __restrict__ W, float* __restrict__ C)
{
  __shared__ __align__(16) char smem[131072];
  const int bid = blockIdx.x;
  const int swb = (bid & 7) * 32 + (bid >> 3);
  const int m0 = (swb & 15) << 8;
  const int n0 = (swb >> 4) << 8;

  f32x4 acc[8][4];
  gemm256_core(A, W, smem, m0, n0, acc);

  const int tid = threadIdx.x, lane = tid & 63, wave = tid >> 6;
  const int l15 = lane & 15, quad = lane >> 4;
  const int wm = wave >> 2, wn = wave & 3;

#pragma unroll
  for (int i = 0; i < 8; i++) {
    const int row = m0 + wm * 128 + i * 16 + quad * 4;
#pragma unroll
    for (int j = 0; j < 4; j++) {
      const int col = n0 + wn * 64 + j * 16 + l15;
#pragma unroll
      for (int r = 0; r < 4; r++)
        C[(size_t)(row + r) * 4096 + col] = acc[i][j][r];
    }
  }
}

// ---------------- fallback QKV GEMM (fp32 inputs, manual staging) ----------------
__global__ __launch_bounds__(256) void gemm_f32in(
    const float* __restrict__ A,
    const float* __restrict__ W0, const float* __restrict__ W1, const float* __restrict__ W2,
    bf16* __restrict__ C0, bf16* __restrict__ C1, bf16* __restrict__ C2)
{
  constexpr int K = 4096, N = 4096;
  __shared__ __align__(16) bf16 As[128 * 32];
  __shared__ __align__(16) bf16 Bs[128 * 32];
  const int z = blockIdx.z;
  const float* __restrict__ W = (z == 0) ? W0 : ((z == 1) ? W1 : W2);
  bf16* __restrict__ C = (z == 0) ? C0 : ((z == 1) ? C1 : C2);
  const int tid = threadIdx.x;
  const int lane = tid & 63, wave = tid >> 6;
  const int l15 = lane & 15, quad = lane >> 4;
  const int m0 = blockIdx.x * 128, n0 = blockIdx.y * 128;
  const int wm = (wave & 1) * 64, wn = (wave >> 1) * 64;

  const int srow = tid >> 2;
  const int scol = (tid & 3) * 8;
  const float* gA = A + (size_t)(m0 + srow) * K + scol;
  const float* gW = W + (size_t)(n0 + srow) * K + scol;
  bf16* lA = &As[srow * 32 + scol];
  bf16* lB = &Bs[srow * 32 + scol];

  f32x4 acc[4][4];
#pragma unroll
  for (int i = 0; i < 4; i++)
#pragma unroll
    for (int j = 0; j < 4; j++) acc[i][j] = (f32x4){0.f, 0.f, 0.f, 0.f};

  for (int k0 = 0; k0 < K; k0 += 32) {
    float4 a0 = *(const float4*)(gA + k0);
    float4 a1 = *(const float4*)(gA + k0 + 4);
    float4 a2 = *(const float4*)(gA + k0 + (size_t)64 * K);
    float4 a3 = *(const float4*)(gA + k0 + (size_t)64 * K + 4);
    float4 b0 = *(const float4*)(gW + k0);
    float4 b1 = *(const float4*)(gW + k0 + 4);
    float4 b2 = *(const float4*)(gW + k0 + (size_t)64 * K);
    float4 b3 = *(const float4*)(gW + k0 + (size_t)64 * K + 4);
    __syncthreads();
    *(bf16x8*)lA              = cvt8(a0, a1);
    *(bf16x8*)(lA + 64 * 32)  = cvt8(a2, a3);
    *(bf16x8*)lB              = cvt8(b0, b1);
    *(bf16x8*)(lB + 64 * 32)  = cvt8(b2, b3);
    __syncthreads();
    bf16x8 af[4], bfr[4];
#pragma unroll
    for (int i = 0; i < 4; i++) af[i]  = *(const bf16x8*)&As[(wm + i * 16 + l15) * 32 + quad * 8];
#pragma unroll
    for (int j = 0; j < 4; j++) bfr[j] = *(const bf16x8*)&Bs[(wn + j * 16 + l15) * 32 + quad * 8];
#pragma unroll
    for (int i = 0; i < 4; i++)
#pragma unroll
      for (int j = 0; j < 4; j++)
        acc[i][j] = MFMA_BF16(af[i], bfr[j], acc[i][j]);
  }

  if (z == 2) {
#pragma unroll
    for (int i = 0; i < 4; i++) {
      const int mg = m0 + wm + i * 16 + quad * 4;
      const int bb = mg >> 11, ss = mg & 2047;
#pragma unroll
      for (int j = 0; j < 4; j++) {
        const int n = n0 + wn + j * 16 + l15;
        ushort4 pk;
        pk.x = __builtin_bit_cast(unsigned short, (bf16)acc[i][j][0]);
        pk.y = __builtin_bit_cast(unsigned short, (bf16)acc[i][j][1]);
        pk.z = __builtin_bit_cast(unsigned short, (bf16)acc[i][j][2]);
        pk.w = __builtin_bit_cast(unsigned short, (bf16)acc[i][j][3]);
        *(ushort4*)&C[((size_t)bb * 4096 + n) * 2048 + ss] = pk;
      }
    }
  } else {
#pragma unroll
    for (int i = 0; i < 4; i++) {
      const int row = m0 + wm + i * 16 + quad * 4;
#pragma unroll
      for (int j = 0; j < 4; j++) {
        const int col = n0 + wn + j * 16 + l15;
#pragma unroll
        for (int r = 0; r < 4; r++)
          C[(size_t)(row + r) * N + col] = (bf16)acc[i][j][r];
      }
    }
  }
}

// Interleaved RoPE on q and k (bf16) in-place; freqs fp32.
__global__ __launch_bounds__(256) void rope_kernel(
    bf16* __restrict__ q, bf16* __restrict__ kk,
    const float* __restrict__ fc, const float* __restrict__ fs)
{
  const int t = blockIdx.x * 256 + threadIdx.x;
  const int i4 = (t & 15) << 2;
  const int row = t >> 4;
  const int s = (row >> 5) & 2047;

  float4 c4 = *(const float4*)(fc + s * 64 + i4);
  float4 s4 = *(const float4*)(fs + s * 64 + i4);
  float c[4]  = {c4.x, c4.y, c4.z, c4.w};
  float sn[4] = {s4.x, s4.y, s4.z, s4.w};

  const int off = row * 128 + (i4 << 1);
  uint4 qv = *(const uint4*)(q + off);
  uint4 kv = *(const uint4*)(kk + off);
  unsigned qa[4] = {qv.x, qv.y, qv.z, qv.w};
  unsigned ka[4] = {kv.x, kv.y, kv.z, kv.w};
#pragma unroll
  for (int p = 0; p < 4; p++) {
    float x0 = __builtin_bit_cast(float, (qa[p] & 0xffffu) << 16);
    float x1 = __builtin_bit_cast(float, (qa[p] >> 16) << 16);
    unsigned lo = __builtin_bit_cast(unsigned short, (bf16)(x0 * c[p] - x1 * sn[p]));
    unsigned hi = __builtin_bit_cast(unsigned short, (bf16)(x0 * sn[p] + x1 * c[p]));
    qa[p] = lo | (hi << 16);
    float y0 = __builtin_bit_cast(float, (ka[p] & 0xffffu) << 16);
    float y1 = __builtin_bit_cast(float, (ka[p] >> 16) << 16);
    lo = __builtin_bit_cast(unsigned short, (bf16)(y0 * c[p] - y1 * sn[p]));
    hi = __builtin_bit_cast(unsigned short, (bf16)(y0 * sn[p] + y1 * c[p]));
    ka[p] = lo | (hi << 16);
  }
  *(uint4*)(q + off)  = make_uint4(qa[0], qa[1], qa[2], qa[3]);
  *(uint4*)(kk + off) = make_uint4(ka[0], ka[1], ka[2], ka[3]);
}

// Flash attention v2: causal, 64 q-rows/block, 128-key chunks, XOR-swizzled LDS.
__global__ __launch_bounds__(256) void flash_attn(
    const bf16* __restrict__ Kg_, const bf16* __restrict__ VT, bf16* __restrict__ QO)
{
  __shared__ __align__(16) char smem[81920];
  bf16* Qs = (bf16*)smem;
  bf16* Ks = (bf16*)(smem + 16384);
  bf16* Vs = (bf16*)(smem + 49152);

  const int tid = threadIdx.x, lane = tid & 63, wave = tid >> 6;
  const int l15 = lane & 15, quad = lane >> 4;
  const int r7 = l15 & 7;
  const int q0 = blockIdx.x * 64, h = blockIdx.y, b = blockIdx.z;

  bf16* Qg       = QO  + ((size_t)(b * 2048 + q0) * 32 + h) * 128;
  const bf16* Kg = Kg_ + ((size_t)b * 2048 * 32 + h) * 128;
  const bf16* Vg = VT  + ((size_t)(b * 32 + h)) * 128 * 2048;

#pragma unroll
  for (int it = 0; it < 4; ++it) {
    int c = it * 256 + tid;
    int rr = c >> 4, cc = (c & 15) ^ (rr & 7);
    gld_lds16(Qg + (size_t)rr * 4096 + cc * 8, &Qs[c * 8]);
  }
  __syncthreads();
  bf16x8 qf[4];
#pragma unroll
  for (int ks = 0; ks < 4; ks++)
    qf[ks] = *(const bf16x8*)&Qs[(wave * 16 + l15) * 128 + (((ks * 4 + quad) ^ r7) * 8)];

  bf16* Ps = (bf16*)smem + wave * (16 * 136);

  float m_i[4], l_i[4];
  f32x4 oacc[8];
#pragma unroll
  for (int r = 0; r < 4; r++) { m_i[r] = -INFINITY; l_i[r] = 0.f; }
#pragma unroll
  for (int j = 0; j < 8; j++) oacc[j] = (f32x4){0.f, 0.f, 0.f, 0.f};

  const float SCL = 0.08838834764831845f * 1.4426950408889634f;

  const int nct = (blockIdx.x >> 1) + 1;
  for (int ct = 0; ct < nct; ++ct) {
    __syncthreads();
    const bf16* Kt = Kg + (size_t)ct * 128 * 4096;
    const bf16* Vt = Vg + ct * 128;
#pragma unroll
    for (int it = 0; it < 8; ++it) {
      int c = it * 256 + tid;
      int rr = c >> 4, cc = (c & 15) ^ (rr & 7);
      gld_lds16(Kt + (size_t)rr * 4096 + cc * 8, &Ks[c * 8]);
      gld_lds16(Vt + (size_t)rr * 2048 + cc * 8, &Vs[c * 8]);
    }
    __syncthreads();

    f32x4 sacc[8];
#pragma unroll
    for (int nb = 0; nb < 8; nb++) {
      f32x4 a = (f32x4){0.f, 0.f, 0.f, 0.f};
#pragma unroll
      for (int ks = 0; ks < 4; ks++) {
        bf16x8 kf = *(const bf16x8*)&Ks[(nb * 16 + l15) * 128 + (((ks * 4 + quad) ^ r7) * 8)];
        a = MFMA_BF16(qf[ks], kf, a);
      }
      sacc[nb] = a;
    }

    const int qb = q0 + wave * 16 + quad * 4;
    const int kbase = ct * 128 + l15;
    float alpha[4];
#pragma unroll
    for (int r = 0; r < 4; r++) {
      float mx = -INFINITY;
#pragma unroll
      for (int nb = 0; nb < 8; nb++) {
        float s = sacc[nb][r] * SCL;
        if (kbase + nb * 16 > qb + r) s = -INFINITY;
        sacc[nb][r] = s;
        mx = fmaxf(mx, s);
      }
#pragma unroll
      for (int off = 1; off < 16; off <<= 1) mx = fmaxf(mx, __shfl_xor(mx, off));
      float mn = fmaxf(m_i[r], mx);
      alpha[r] = exp2f(m_i[r] - mn);
      m_i[r] = mn;
      float rs = 0.f;
#pragma unroll
      for (int nb = 0; nb < 8; nb++) {
        float p = exp2f(sacc[nb][r] - mn);
        rs += p;
        Ps[(quad * 4 + r) * 136 + nb * 16 + l15] = (bf16)p;
      }
#pragma unroll
      for (int off = 1; off < 16; off <<= 1) rs += __shfl_xor(rs, off);
      l_i[r] = l_i[r] * alpha[r] + rs;
    }
#pragma unroll
    for (int j = 0; j < 8; j++)
#pragma unroll
      for (int r = 0; r < 4; r++) oacc[j][r] *= alpha[r];

    __syncthreads();

#pragma unroll
    for (int ks2 = 0; ks2 < 4; ks2++) {
      bf16x8 pf = *(const bf16x8*)&Ps[l15 * 136 + ks2 * 32 + quad * 8];
#pragma unroll
      for (int j = 0; j < 8; j++) {
        bf16x8 vf = *(const bf16x8*)&Vs[(j * 16 + l15) * 128 + (((ks2 * 4 + quad) ^ r7) * 8)];
        oacc[j] = MFMA_BF16(pf, vf, oacc[j]);
      }
    }
  }

#pragma unroll
  for (int r = 0; r < 4; r++) {
    const float inv = 1.f / l_i[r];
    const int row = q0 + wave * 16 + quad * 4 + r;
    bf16* Og = QO + ((size_t)(b * 2048 + row) * 32 + h) * 128;
#pragma unroll
    for (int j = 0; j < 8; j++) Og[j * 16 + l15] = (bf16)(oacc[j][r] * inv);
  }
}

extern "C" void kernel_launch(void* const* d_in, const int* in_sizes, int n_in,
                              void* d_out, int out_size, void* d_ws, size_t ws_size,
                              hipStream_t stream) {
  const float* x  = (const float*)d_in[0];
  const float* wq = (const float*)d_in[1];
  const float* wk = (const float*)d_in[2];
  const float* wv = (const float*)d_in[3];
  const float* wo = (const float*)d_in[4];
  const float* fc = (const float*)d_in[5];
  const float* fs = (const float*)d_in[6];
  float* out = (float*)d_out;

  float sentinel = 0.f;
  if (n_in < 9 || in_sizes[0] != 16777216) sentinel = 200.f;
  else if (out_size != 16777216)           sentinel = 300.f;
  else if (in_sizes[5] != 131072)          sentinel = 400.f;
  else if (ws_size < 3ull * 33554432ull)   sentinel = 100.f;
  if (sentinel != 0.f) {
    fill_kernel<<<dim3((out_size + 255) / 256), dim3(256), 0, stream>>>(out, out_size, sentinel);
    return;
  }

  bf16* q  = (bf16*)d_ws;                    // becomes attention output in-place
  bf16* k  = q  + (size_t)16777216;          // later reused for bf16(wo)
  bf16* vt = k  + (size_t)16777216;

  dim3 blk(256, 1, 1);
  dim3 blk512(512, 1, 1);
  const bool bigws = (ws_size >= 7ull * 33554432ull);   // 224 MiB

  if (bigws) {
    bf16* xb  = vt  + (size_t)16777216;
    bf16* wqb = xb  + (size_t)16777216;
    bf16* wkb = wqb + (size_t)16777216;
    bf16* wvb = wkb + (size_t)16777216;
    cvt_kernel<<<dim3(16384), blk, 0, stream>>>(x,  xb);
    cvt_kernel<<<dim3(16384), blk, 0, stream>>>(wq, wqb);
    cvt_kernel<<<dim3(16384), blk, 0, stream>>>(wk, wkb);
    cvt_kernel<<<dim3(16384), blk, 0, stream>>>(wv, wvb);
    gemm256_qkv<<<dim3(256, 1, 3), blk512, 0, stream>>>(xb, wqb, wkb, wvb, q, k, vt);
  } else {
    gemm_f32in<<<dim3(32, 32, 3), blk, 0, stream>>>(x, wq, wk, wv, q, k, vt);
  }
  rope_kernel<<<dim3(8192), blk, 0, stream>>>(q, k, fc, fs);
  flash_attn<<<dim3(32, 32, 2), blk, 0, stream>>>(k, vt, q);
  cvt_kernel<<<dim3(16384), blk, 0, stream>>>(wo, k);          // k buffer now dead -> bf16(wo)
  gemm256_out<<<dim3(256, 1, 1), blk512, 0, stream>>>(q, k, out);
}

// Round 3
// 1121.135 us; speedup vs baseline: 1.3817x; 1.0509x over previous
//
#include <hip/hip_runtime.h>

typedef __bf16 bf16;
typedef __attribute__((ext_vector_type(8))) __bf16 bf16x8;
typedef __attribute__((ext_vector_type(4))) float f32x4;

#define MFMA_BF16(a,b,c) __builtin_amdgcn_mfma_f32_16x16x32_bf16((a),(b),(c),0,0,0)

__device__ __forceinline__ void gld_lds16(const void* g, void* l) {
  __builtin_amdgcn_global_load_lds(
      (__attribute__((address_space(1))) void*)(g),
      (__attribute__((address_space(3))) void*)(l), 16, 0, 0);
}

__device__ __forceinline__ bf16x8 cvt8(float4 u, float4 v) {
  bf16x8 r;
  r[0] = (bf16)u.x; r[1] = (bf16)u.y; r[2] = (bf16)u.z; r[3] = (bf16)u.w;
  r[4] = (bf16)v.x; r[5] = (bf16)v.y; r[6] = (bf16)v.z; r[7] = (bf16)v.w;
  return r;
}

__global__ __launch_bounds__(256) void fill_kernel(float* p, int n, float v) {
  int i = blockIdx.x * 256 + threadIdx.x;
  if (i < n) p[i] = v;
}

// fp32 -> bf16, 4 elems/thread
__global__ __launch_bounds__(256) void cvt_kernel(const float* __restrict__ s, bf16* __restrict__ d) {
  size_t i = ((size_t)blockIdx.x * 256 + threadIdx.x) * 4;
  float4 a = *(const float4*)(s + i);
  ushort4 r;
  r.x = __builtin_bit_cast(unsigned short, (bf16)a.x);
  r.y = __builtin_bit_cast(unsigned short, (bf16)a.y);
  r.z = __builtin_bit_cast(unsigned short, (bf16)a.z);
  r.w = __builtin_bit_cast(unsigned short, (bf16)a.w);
  *(ushort4*)(d + i) = r;
}

// ================= 256x256 8-wave deep-pipeline GEMM core =================
// C[m][n] = sum_k A[m][k]*W[n][k], K = N = 4096, BK = 64.
// LDS = 8 ring slots of 16K: [buf][op A/B][ks], buf = t&1.
// Slot refilled 2 tiles ahead, right after its last reader:
//   tile s: P0 stages A.k1(s+1); P1: B.k0(s+2); P2: A.k0(s+2); P3: B.k1(s+2)
// Steady-state gates: vmcnt(10) at G0/G1 (5 stage-ops = 10 loads in flight),
// issue-to-consume distance 6-7 phases. Tail peeled: t=NT-2 (10,8), t=NT-1 (4,0).
// XOR swizzle within each slot (conflict-free ds_read_b128); staging pre-swizzles
// the per-lane GLOBAL source, LDS dest stays linear (rule 21).

template<int IH, int KS>
__device__ __forceinline__ void mfma_phase(const char* rb, int sA, int sB,
                                           f32x4 (&acc)[8][4], bf16x8 (&bq)[4])
{
  bf16x8 afr[4];
#pragma unroll
  for (int i2 = 0; i2 < 4; ++i2)
    afr[i2] = *(const bf16x8*)(rb + KS * 16384 + sA + (IH * 4 + i2) * 1024);
  if (IH == 0) {
#pragma unroll
    for (int j = 0; j < 4; ++j)
      bq[j] = *(const bf16x8*)(rb + 32768 + KS * 16384 + sB + j * 1024);
  }
  __builtin_amdgcn_s_barrier();
  __builtin_amdgcn_s_setprio(1);
#pragma unroll
  for (int i2 = 0; i2 < 4; ++i2)
#pragma unroll
    for (int j = 0; j < 4; ++j)
      acc[IH * 4 + i2][j] = MFMA_BF16(afr[i2], bq[j], acc[IH * 4 + i2][j]);
  __builtin_amdgcn_s_setprio(0);
}

__device__ __forceinline__ void gemm256_core(
    const bf16* __restrict__ Ag, const bf16* __restrict__ Wg,
    char* smem, int m0, int n0, f32x4 (&acc)[8][4])
{
  constexpr int NT = 64;   // 4096 / 64
  const int tid = threadIdx.x;                 // 0..511
  const int lane = tid & 63;
  const int l15 = lane & 15, quad = lane >> 4;
  const int wave = tid >> 6;
  const int wm = wave >> 2, wn = wave & 3;

  // per-lane ds_read base byte offsets within a 16K (op,ks) slot
  const int swz = (((l15 & 1) * 4 + quad) ^ (l15 >> 1));
  const int sA = ((wm * 64 + (l15 >> 1)) * 8 + swz) * 16;
  const int sB = ((wn * 32 + (l15 >> 1)) * 8 + swz) * 16;

  // stage source decomposition (pre-swizzled global addr for linear LDS slot)
  int r0, c0, r1, c1;
  { int s = tid;       int rp = s >> 3, y = (s & 7) ^ (rp & 7); r0 = rp * 2 + (y >> 2); c0 = y & 3; }
  { int s = 512 + tid; int rp = s >> 3, y = (s & 7) ^ (rp & 7); r1 = rp * 2 + (y >> 2); c1 = y & 3; }

  const bf16* gA0 = Ag + (size_t)(m0 + r0) * 4096 + c0 * 8;
  const bf16* gA1 = Ag + (size_t)(m0 + r1) * 4096 + c1 * 8;
  const bf16* gB0 = Wg + (size_t)(n0 + r0) * 4096 + c0 * 8;
  const bf16* gB1 = Wg + (size_t)(n0 + r1) * 4096 + c1 * 8;

  const int d0 = tid * 16, d1 = (512 + tid) * 16;

  // one stage-op = 2 global_load_lds (slot for tile t2)
  auto stA = [&](int t2, int ks) {
    char* L = smem + (t2 & 1) * 65536 + ks * 16384;
    gld_lds16(gA0 + t2 * 64 + ks * 32, L + d0);
    gld_lds16(gA1 + t2 * 64 + ks * 32, L + d1);
  };
  auto stB = [&](int t2, int ks) {
    char* L = smem + (t2 & 1) * 65536 + 32768 + ks * 16384;
    gld_lds16(gB0 + t2 * 64 + ks * 32, L + d0);
    gld_lds16(gB1 + t2 * 64 + ks * 32, L + d1);
  };

#pragma unroll
  for (int i = 0; i < 8; i++)
#pragma unroll
    for (int j = 0; j < 4; j++) acc[i][j] = (f32x4){0.f, 0.f, 0.f, 0.f};

  // prologue: FIFO order defines vmcnt counting
  stB(0, 0); stA(0, 0); stB(0, 1); stA(0, 1); stB(1, 0); stA(1, 0); stB(1, 1);

#pragma unroll 2
  for (int t = 0; t < NT - 2; ++t) {
    const char* rb = smem + (t & 1) * 65536;

    asm volatile("s_waitcnt vmcnt(10)" ::: "memory");   // G0: A.k0(t), B.k0(t) landed
    __builtin_amdgcn_s_barrier();

    bf16x8 bq0[4];
    stA(t + 1, 1);                       // P0: refill A.k1 slot of other buf
    mfma_phase<0, 0>(rb, sA, sB, acc, bq0);
    __builtin_amdgcn_s_barrier();

    stB(t + 2, 0);                       // P1: refill B.k0 (this buf, consumed in P0)
    mfma_phase<1, 0>(rb, sA, sB, acc, bq0);

    asm volatile("s_waitcnt vmcnt(10)" ::: "memory");   // G1: A.k1(t), B.k1(t) landed
    __builtin_amdgcn_s_barrier();

    bf16x8 bq1[4];
    stA(t + 2, 0);                       // P2: refill A.k0 (consumed in P0/P1)
    mfma_phase<0, 1>(rb, sA, sB, acc, bq1);
    __builtin_amdgcn_s_barrier();

    stB(t + 2, 1);                       // P3: refill B.k1 (consumed in P2)
    mfma_phase<1, 1>(rb, sA, sB, acc, bq1);
  }

  // t = NT-2 (parity 0)
  {
    const char* rb = smem;
    asm volatile("s_waitcnt vmcnt(10)" ::: "memory");
    __builtin_amdgcn_s_barrier();
    bf16x8 bq0[4];
    stA(NT - 1, 1);
    mfma_phase<0, 0>(rb, sA, sB, acc, bq0);
    __builtin_amdgcn_s_barrier();
    mfma_phase<1, 0>(rb, sA, sB, acc, bq0);
    asm volatile("s_waitcnt vmcnt(8)" ::: "memory");
    __builtin_amdgcn_s_barrier();
    bf16x8 bq1[4];
    mfma_phase<0, 1>(rb, sA, sB, acc, bq1);
    __builtin_amdgcn_s_barrier();
    mfma_phase<1, 1>(rb, sA, sB, acc, bq1);
  }
  // t = NT-1 (parity 1)
  {
    const char* rb = smem + 65536;
    asm volatile("s_waitcnt vmcnt(4)" ::: "memory");
    __builtin_amdgcn_s_barrier();
    bf16x8 bq0[4];
    mfma_phase<0, 0>(rb, sA, sB, acc, bq0);
    __builtin_amdgcn_s_barrier();
    mfma_phase<1, 0>(rb, sA, sB, acc, bq0);
    asm volatile("s_waitcnt vmcnt(0)" ::: "memory");
    __builtin_amdgcn_s_barrier();
    bf16x8 bq1[4];
    mfma_phase<0, 1>(rb, sA, sB, acc, bq1);
    __builtin_amdgcn_s_barrier();
    mfma_phase<1, 1>(rb, sA, sB, acc, bq1);
  }
}

// QKV triple GEMM, bf16 out; z==2 -> VT transposed epilogue (b,h,d,s)
__global__ __launch_bounds__(512) void gemm256_qkv(
    const bf16* __restrict__ A,
    const bf16* __restrict__ W0, const bf16* __restrict__ W1, const bf16* __restrict__ W2,
    bf16* __restrict__ C0, bf16* __restrict__ C1, bf16* __restrict__ C2)
{
  __shared__ __align__(16) char smem[131072];
  const int z = blockIdx.z;
  const bf16* __restrict__ W = (z == 0) ? W0 : ((z == 1) ? W1 : W2);
  bf16* __restrict__ C = (z == 0) ? C0 : ((z == 1) ? C1 : C2);

  const int bid = blockIdx.x;                  // 0..255
  const int swb = (bid & 7) * 32 + (bid >> 3); // bijective XCD swizzle
  const int m0 = (swb & 15) << 8;
  const int n0 = (swb >> 4) << 8;

  f32x4 acc[8][4];
  gemm256_core(A, W, smem, m0, n0, acc);

  const int tid = threadIdx.x, lane = tid & 63, wave = tid >> 6;
  const int l15 = lane & 15, quad = lane >> 4;
  const int wm = wave >> 2, wn = wave & 3;

  if (z == 2) {
#pragma unroll
    for (int i = 0; i < 8; i++) {
      const int mg = m0 + wm * 128 + i * 16 + quad * 4;
      const int bb = mg >> 11, ss = mg & 2047;
#pragma unroll
      for (int j = 0; j < 4; j++) {
        const int n = n0 + wn * 64 + j * 16 + l15;
        ushort4 pk;
        pk.x = __builtin_bit_cast(unsigned short, (bf16)acc[i][j][0]);
        pk.y = __builtin_bit_cast(unsigned short, (bf16)acc[i][j][1]);
        pk.z = __builtin_bit_cast(unsigned short, (bf16)acc[i][j][2]);
        pk.w = __builtin_bit_cast(unsigned short, (bf16)acc[i][j][3]);
        *(ushort4*)&C[((size_t)bb * 4096 + n) * 2048 + ss] = pk;
      }
    }
  } else {
#pragma unroll
    for (int i = 0; i < 8; i++) {
      const int row = m0 + wm * 128 + i * 16 + quad * 4;
#pragma unroll
      for (int j = 0; j < 4; j++) {
        const int col = n0 + wn * 64 + j * 16 + l15;
#pragma unroll
        for (int r = 0; r < 4; r++)
          C[(size_t)(row + r) * 4096 + col] = (bf16)acc[i][j][r];
      }
    }
  }
}

// single GEMM, fp32 out
__global__ __launch_bounds__(512) void gemm256_out(
    const bf16* __restrict__ A, const bf16* __restrict__ W, float* __restrict__ C)
{
  __shared__ __align__(16) char smem[131072];
  const int bid = blockIdx.x;
  const int swb = (bid & 7) * 32 + (bid >> 3);
  const int m0 = (swb & 15) << 8;
  const int n0 = (swb >> 4) << 8;

  f32x4 acc[8][4];
  gemm256_core(A, W, smem, m0, n0, acc);

  const int tid = threadIdx.x, lane = tid & 63, wave = tid >> 6;
  const int l15 = lane & 15, quad = lane >> 4;
  const int wm = wave >> 2, wn = wave & 3;

#pragma unroll
  for (int i = 0; i < 8; i++) {
    const int row = m0 + wm * 128 + i * 16 + quad * 4;
#pragma unroll
    for (int j = 0; j < 4; j++) {
      const int col = n0 + wn * 64 + j * 16 + l15;
#pragma unroll
      for (int r = 0; r < 4; r++)
        C[(size_t)(row + r) * 4096 + col] = acc[i][j][r];
    }
  }
}

// ---------------- fallback QKV GEMM (fp32 inputs, manual staging) ----------------
__global__ __launch_bounds__(256) void gemm_f32in(
    const float* __restrict__ A,
    const float* __restrict__ W0, const float* __restrict__ W1, const float* __restrict__ W2,
    bf16* __restrict__ C0, bf16* __restrict__ C1, bf16* __restrict__ C2)
{
  constexpr int K = 4096, N = 4096;
  __shared__ __align__(16) bf16 As[128 * 32];
  __shared__ __align__(16) bf16 Bs[128 * 32];
  const int z = blockIdx.z;
  const float* __restrict__ W = (z == 0) ? W0 : ((z == 1) ? W1 : W2);
  bf16* __restrict__ C = (z == 0) ? C0 : ((z == 1) ? C1 : C2);
  const int tid = threadIdx.x;
  const int lane = tid & 63, wave = tid >> 6;
  const int l15 = lane & 15, quad = lane >> 4;
  const int m0 = blockIdx.x * 128, n0 = blockIdx.y * 128;
  const int wm = (wave & 1) * 64, wn = (wave >> 1) * 64;

  const int srow = tid >> 2;
  const int scol = (tid & 3) * 8;
  const float* gA = A + (size_t)(m0 + srow) * K + scol;
  const float* gW = W + (size_t)(n0 + srow) * K + scol;
  bf16* lA = &As[srow * 32 + scol];
  bf16* lB = &Bs[srow * 32 + scol];

  f32x4 acc[4][4];
#pragma unroll
  for (int i = 0; i < 4; i++)
#pragma unroll
    for (int j = 0; j < 4; j++) acc[i][j] = (f32x4){0.f, 0.f, 0.f, 0.f};

  for (int k0 = 0; k0 < K; k0 += 32) {
    float4 a0 = *(const float4*)(gA + k0);
    float4 a1 = *(const float4*)(gA + k0 + 4);
    float4 a2 = *(const float4*)(gA + k0 + (size_t)64 * K);
    float4 a3 = *(const float4*)(gA + k0 + (size_t)64 * K + 4);
    float4 b0 = *(const float4*)(gW + k0);
    float4 b1 = *(const float4*)(gW + k0 + 4);
    float4 b2 = *(const float4*)(gW + k0 + (size_t)64 * K);
    float4 b3 = *(const float4*)(gW + k0 + (size_t)64 * K + 4);
    __syncthreads();
    *(bf16x8*)lA              = cvt8(a0, a1);
    *(bf16x8*)(lA + 64 * 32)  = cvt8(a2, a3);
    *(bf16x8*)lB              = cvt8(b0, b1);
    *(bf16x8*)(lB + 64 * 32)  = cvt8(b2, b3);
    __syncthreads();
    bf16x8 af[4], bfr[4];
#pragma unroll
    for (int i = 0; i < 4; i++) af[i]  = *(const bf16x8*)&As[(wm + i * 16 + l15) * 32 + quad * 8];
#pragma unroll
    for (int j = 0; j < 4; j++) bfr[j] = *(const bf16x8*)&Bs[(wn + j * 16 + l15) * 32 + quad * 8];
#pragma unroll
    for (int i = 0; i < 4; i++)
#pragma unroll
      for (int j = 0; j < 4; j++)
        acc[i][j] = MFMA_BF16(af[i], bfr[j], acc[i][j]);
  }

  if (z == 2) {
#pragma unroll
    for (int i = 0; i < 4; i++) {
      const int mg = m0 + wm + i * 16 + quad * 4;
      const int bb = mg >> 11, ss = mg & 2047;
#pragma unroll
      for (int j = 0; j < 4; j++) {
        const int n = n0 + wn + j * 16 + l15;
        ushort4 pk;
        pk.x = __builtin_bit_cast(unsigned short, (bf16)acc[i][j][0]);
        pk.y = __builtin_bit_cast(unsigned short, (bf16)acc[i][j][1]);
        pk.z = __builtin_bit_cast(unsigned short, (bf16)acc[i][j][2]);
        pk.w = __builtin_bit_cast(unsigned short, (bf16)acc[i][j][3]);
        *(ushort4*)&C[((size_t)bb * 4096 + n) * 2048 + ss] = pk;
      }
    }
  } else {
#pragma unroll
    for (int i = 0; i < 4; i++) {
      const int row = m0 + wm + i * 16 + quad * 4;
#pragma unroll
      for (int j = 0; j < 4; j++) {
        const int col = n0 + wn + j * 16 + l15;
#pragma unroll
        for (int r = 0; r < 4; r++)
          C[(size_t)(row + r) * N + col] = (bf16)acc[i][j][r];
      }
    }
  }
}

// Interleaved RoPE on q and k (bf16) in-place; freqs fp32.
__global__ __launch_bounds__(256) void rope_kernel(
    bf16* __restrict__ q, bf16* __restrict__ kk,
    const float* __restrict__ fc, const float* __restrict__ fs)
{
  const int t = blockIdx.x * 256 + threadIdx.x;
  const int i4 = (t & 15) << 2;
  const int row = t >> 4;
  const int s = (row >> 5) & 2047;

  float4 c4 = *(const float4*)(fc + s * 64 + i4);
  float4 s4 = *(const float4*)(fs + s * 64 + i4);
  float c[4]  = {c4.x, c4.y, c4.z, c4.w};
  float sn[4] = {s4.x, s4.y, s4.z, s4.w};

  const int off = row * 128 + (i4 << 1);
  uint4 qv = *(const uint4*)(q + off);
  uint4 kv = *(const uint4*)(kk + off);
  unsigned qa[4] = {qv.x, qv.y, qv.z, qv.w};
  unsigned ka[4] = {kv.x, kv.y, kv.z, kv.w};
#pragma unroll
  for (int p = 0; p < 4; p++) {
    float x0 = __builtin_bit_cast(float, (qa[p] & 0xffffu) << 16);
    float x1 = __builtin_bit_cast(float, (qa[p] >> 16) << 16);
    unsigned lo = __builtin_bit_cast(unsigned short, (bf16)(x0 * c[p] - x1 * sn[p]));
    unsigned hi = __builtin_bit_cast(unsigned short, (bf16)(x0 * sn[p] + x1 * c[p]));
    qa[p] = lo | (hi << 16);
    float y0 = __builtin_bit_cast(float, (ka[p] & 0xffffu) << 16);
    float y1 = __builtin_bit_cast(float, (ka[p] >> 16) << 16);
    lo = __builtin_bit_cast(unsigned short, (bf16)(y0 * c[p] - y1 * sn[p]));
    hi = __builtin_bit_cast(unsigned short, (bf16)(y0 * sn[p] + y1 * c[p]));
    ka[p] = lo | (hi << 16);
  }
  *(uint4*)(q + off)  = make_uint4(qa[0], qa[1], qa[2], qa[3]);
  *(uint4*)(kk + off) = make_uint4(ka[0], ka[1], ka[2], ka[3]);
}

// Flash attention v2: causal, 64 q-rows/block, 128-key chunks, XOR-swizzled LDS.
__global__ __launch_bounds__(256) void flash_attn(
    const bf16* __restrict__ Kg_, const bf16* __restrict__ VT, bf16* __restrict__ QO)
{
  __shared__ __align__(16) char smem[81920];
  bf16* Qs = (bf16*)smem;
  bf16* Ks = (bf16*)(smem + 16384);
  bf16* Vs = (bf16*)(smem + 49152);

  const int tid = threadIdx.x, lane = tid & 63, wave = tid >> 6;
  const int l15 = lane & 15, quad = lane >> 4;
  const int r7 = l15 & 7;
  const int q0 = blockIdx.x * 64, h = blockIdx.y, b = blockIdx.z;

  bf16* Qg       = QO  + ((size_t)(b * 2048 + q0) * 32 + h) * 128;
  const bf16* Kg = Kg_ + ((size_t)b * 2048 * 32 + h) * 128;
  const bf16* Vg = VT  + ((size_t)(b * 32 + h)) * 128 * 2048;

#pragma unroll
  for (int it = 0; it < 4; ++it) {
    int c = it * 256 + tid;
    int rr = c >> 4, cc = (c & 15) ^ (rr & 7);
    gld_lds16(Qg + (size_t)rr * 4096 + cc * 8, &Qs[c * 8]);
  }
  __syncthreads();
  bf16x8 qf[4];
#pragma unroll
  for (int ks = 0; ks < 4; ks++)
    qf[ks] = *(const bf16x8*)&Qs[(wave * 16 + l15) * 128 + (((ks * 4 + quad) ^ r7) * 8)];

  bf16* Ps = (bf16*)smem + wave * (16 * 136);

  float m_i[4], l_i[4];
  f32x4 oacc[8];
#pragma unroll
  for (int r = 0; r < 4; r++) { m_i[r] = -INFINITY; l_i[r] = 0.f; }
#pragma unroll
  for (int j = 0; j < 8; j++) oacc[j] = (f32x4){0.f, 0.f, 0.f, 0.f};

  const float SCL = 0.08838834764831845f * 1.4426950408889634f;

  const int nct = (blockIdx.x >> 1) + 1;
  for (int ct = 0; ct < nct; ++ct) {
    __syncthreads();
    const bf16* Kt = Kg + (size_t)ct * 128 * 4096;
    const bf16* Vt = Vg + ct * 128;
#pragma unroll
    for (int it = 0; it < 8; ++it) {
      int c = it * 256 + tid;
      int rr = c >> 4, cc = (c & 15) ^ (rr & 7);
      gld_lds16(Kt + (size_t)rr * 4096 + cc * 8, &Ks[c * 8]);
      gld_lds16(Vt + (size_t)rr * 2048 + cc * 8, &Vs[c * 8]);
    }
    __syncthreads();

    f32x4 sacc[8];
#pragma unroll
    for (int nb = 0; nb < 8; nb++) {
      f32x4 a = (f32x4){0.f, 0.f, 0.f, 0.f};
#pragma unroll
      for (int ks = 0; ks < 4; ks++) {
        bf16x8 kf = *(const bf16x8*)&Ks[(nb * 16 + l15) * 128 + (((ks * 4 + quad) ^ r7) * 8)];
        a = MFMA_BF16(qf[ks], kf, a);
      }
      sacc[nb] = a;
    }

    const int qb = q0 + wave * 16 + quad * 4;
    const int kbase = ct * 128 + l15;
    float alpha[4];
#pragma unroll
    for (int r = 0; r < 4; r++) {
      float mx = -INFINITY;
#pragma unroll
      for (int nb = 0; nb < 8; nb++) {
        float s = sacc[nb][r] * SCL;
        if (kbase + nb * 16 > qb + r) s = -INFINITY;
        sacc[nb][r] = s;
        mx = fmaxf(mx, s);
      }
#pragma unroll
      for (int off = 1; off < 16; off <<= 1) mx = fmaxf(mx, __shfl_xor(mx, off));
      float mn = fmaxf(m_i[r], mx);
      alpha[r] = exp2f(m_i[r] - mn);
      m_i[r] = mn;
      float rs = 0.f;
#pragma unroll
      for (int nb = 0; nb < 8; nb++) {
        float p = exp2f(sacc[nb][r] - mn);
        rs += p;
        Ps[(quad * 4 + r) * 136 + nb * 16 + l15] = (bf16)p;
      }
#pragma unroll
      for (int off = 1; off < 16; off <<= 1) rs += __shfl_xor(rs, off);
      l_i[r] = l_i[r] * alpha[r] + rs;
    }
#pragma unroll
    for (int j = 0; j < 8; j++)
#pragma unroll
      for (int r = 0; r < 4; r++) oacc[j][r] *= alpha[r];

    __syncthreads();

#pragma unroll
    for (int ks2 = 0; ks2 < 4; ks2++) {
      bf16x8 pf = *(const bf16x8*)&Ps[l15 * 136 + ks2 * 32 + quad * 8];
#pragma unroll
      for (int j = 0; j < 8; j++) {
        bf16x8 vf = *(const bf16x8*)&Vs[(j * 16 + l15) * 128 + (((ks2 * 4 + quad) ^ r7) * 8)];
        oacc[j] = MFMA_BF16(pf, vf, oacc[j]);
      }
    }
  }

#pragma unroll
  for (int r = 0; r < 4; r++) {
    const float inv = 1.f / l_i[r];
    const int row = q0 + wave * 16 + quad * 4 + r;
    bf16* Og = QO + ((size_t)(b * 2048 + row) * 32 + h) * 128;
#pragma unroll
    for (int j = 0; j < 8; j++) Og[j * 16 + l15] = (bf16)(oacc[j][r] * inv);
  }
}

extern "C" void kernel_launch(void* const* d_in, const int* in_sizes, int n_in,
                              void* d_out, int out_size, void* d_ws, size_t ws_size,
                              hipStream_t stream) {
  const float* x  = (const float*)d_in[0];
  const float* wq = (const float*)d_in[1];
  const float* wk = (const float*)d_in[2];
  const float* wv = (const float*)d_in[3];
  const float* wo = (const float*)d_in[4];
  const float* fc = (const float*)d_in[5];
  const float* fs = (const float*)d_in[6];
  float* out = (float*)d_out;

  float sentinel = 0.f;
  if (n_in < 9 || in_sizes[0] != 16777216) sentinel = 200.f;
  else if (out_size != 16777216)           sentinel = 300.f;
  else if (in_sizes[5] != 131072)          sentinel = 400.f;
  else if (ws_size < 3ull * 33554432ull)   sentinel = 100.f;
  if (sentinel != 0.f) {
    fill_kernel<<<dim3((out_size + 255) / 256), dim3(256), 0, stream>>>(out, out_size, sentinel);
    return;
  }

  bf16* q  = (bf16*)d_ws;                    // becomes attention output in-place
  bf16* k  = q  + (size_t)16777216;          // later reused for bf16(wo)
  bf16* vt = k  + (size_t)16777216;

  dim3 blk(256, 1, 1);
  dim3 blk512(512, 1, 1);
  const bool bigws = (ws_size >= 7ull * 33554432ull);   // 224 MiB

  if (bigws) {
    bf16* xb  = vt  + (size_t)16777216;
    bf16* wqb = xb  + (size_t)16777216;
    bf16* wkb = wqb + (size_t)16777216;
    bf16* wvb = wkb + (size_t)16777216;
    cvt_kernel<<<dim3(16384), blk, 0, stream>>>(x,  xb);
    cvt_kernel<<<dim3(16384), blk, 0, stream>>>(wq, wqb);
    cvt_kernel<<<dim3(16384), blk, 0, stream>>>(wk, wkb);
    cvt_kernel<<<dim3(16384), blk, 0, stream>>>(wv, wvb);
    gemm256_qkv<<<dim3(256, 1, 3), blk512, 0, stream>>>(xb, wqb, wkb, wvb, q, k, vt);
  } else {
    gemm_f32in<<<dim3(32, 32, 3), blk, 0, stream>>>(x, wq, wk, wv, q, k, vt);
  }
  rope_kernel<<<dim3(8192), blk, 0, stream>>>(q, k, fc, fs);
  flash_attn<<<dim3(32, 32, 2), blk, 0, stream>>>(k, vt, q);
  cvt_kernel<<<dim3(16384), blk, 0, stream>>>(wo, k);          // k buffer now dead -> bf16(wo)
  gemm256_out<<<dim3(256, 1, 1), blk512, 0, stream>>>(q, k, out);
}